// Round 8
// baseline (467.709 us; speedup 1.0000x reference)
//
#include <hip/hip_runtime.h>
#include <hip/hip_bf16.h>

#define N_NODES 50000
#define N_EDGES 1600000
#define NEG_SLOPE 0.01f
#define WPAD 136   // k-stride (fp16) for LDS-staged W

#define NBKT 256   // dst buckets
#define BKTW 196   // bucket width: 196*256 = 50176 >= 50000
#define NBLK1 200  // pass-1 blocks
#define CHUNK1 8000 // 200*8000 = 1.6M edges exactly

typedef _Float16 v8h __attribute__((ext_vector_type(8)));
typedef _Float16 v2h __attribute__((ext_vector_type(2)));
typedef float v4f __attribute__((ext_vector_type(4)));

// ---------------------------------------------------------------------------
// proj: z[n, h*16+col] = sum_d x[n,d] * W[h,d,col], fp16 MFMA 16x16x32.
// ---------------------------------------------------------------------------
__global__ __launch_bounds__(256) void proj_mfma_kernel(
    const float* __restrict__ x,
    const float* __restrict__ W,
    _Float16* __restrict__ z)
{
    __shared__ _Float16 Wl[128 * WPAD];

    const int t = threadIdx.x;
    for (int i = t; i < 16384; i += 256) {
        const int h = i >> 11, k = (i >> 4) & 127, col = i & 15;
        Wl[(h * 16 + col) * WPAD + k] = (_Float16)W[i];
    }
    __syncthreads();

    const int wid = t >> 6;
    const int l   = t & 63;
    const int lc  = l & 15;
    const int kg  = l >> 4;

    const int nwaves = gridDim.x * 4;
    for (int tile = blockIdx.x * 4 + wid; tile < N_NODES / 16; tile += nwaves) {
        const int n0 = tile * 16;
        v4f acc[8];
#pragma unroll
        for (int ht = 0; ht < 8; ht++) acc[ht] = (v4f)0.f;

#pragma unroll
        for (int kb = 0; kb < 4; kb++) {
            const float4* xp = (const float4*)&x[(n0 + lc) * 128 + kb * 32 + kg * 8];
            const float4 xa = xp[0];
            const float4 xb = xp[1];
            v8h a;
            a[0] = (_Float16)xa.x; a[1] = (_Float16)xa.y;
            a[2] = (_Float16)xa.z; a[3] = (_Float16)xa.w;
            a[4] = (_Float16)xb.x; a[5] = (_Float16)xb.y;
            a[6] = (_Float16)xb.z; a[7] = (_Float16)xb.w;
#pragma unroll
            for (int ht = 0; ht < 8; ht++) {
                const v8h b = *(const v8h*)&Wl[(ht * 16 + lc) * WPAD + kb * 32 + kg * 8];
                acc[ht] = __builtin_amdgcn_mfma_f32_16x16x32_f16(a, b, acc[ht], 0, 0, 0);
            }
        }

        _Float16* zp = &z[(n0 + 4 * kg) * 128 + lc];
#pragma unroll
        for (int ht = 0; ht < 8; ht++)
#pragma unroll
            for (int i = 0; i < 4; i++)
                zp[i * 128 + ht * 16] = (_Float16)acc[ht][i];
    }
}

// ---------------------------------------------------------------------------
// score: s_src[n,h], s_dst[n,h] from fp16 z.
// ---------------------------------------------------------------------------
__global__ __launch_bounds__(256) void score_kernel(
    const _Float16* __restrict__ z,
    const float* __restrict__ a_src, const float* __restrict__ a_dst,
    float* __restrict__ s_src, float* __restrict__ s_dst)
{
    __shared__ float asl[128], adl[128];
    const int t = threadIdx.x;
    if (t < 128) { asl[t] = a_src[t]; adl[t] = a_dst[t]; }
    __syncthreads();

    const int idx = blockIdx.x * 256 + t;
    if (idx >= N_NODES * 8) return;
    const int n = idx >> 3, h = idx & 7;

    const v8h z0 = *(const v8h*)&z[n * 128 + h * 16];
    const v8h z1 = *(const v8h*)&z[n * 128 + h * 16 + 8];
    float ss = 0.f, sd = 0.f;
#pragma unroll
    for (int j = 0; j < 8; j++) {
        ss = fmaf((float)z0[j], asl[h * 16 + j], ss);
        sd = fmaf((float)z0[j], adl[h * 16 + j], sd);
    }
#pragma unroll
    for (int j = 0; j < 8; j++) {
        ss = fmaf((float)z1[j], asl[h * 16 + 8 + j], ss);
        sd = fmaf((float)z1[j], adl[h * 16 + 8 + j], sd);
    }
    s_src[idx] = ss;
    s_dst[idx] = sd;
}

// ---------------------------------------------------------------------------
// CSR build: two-level bucket sort, block-local writes.
// ---------------------------------------------------------------------------
__global__ __launch_bounds__(256) void hist_bucket_kernel(
    const int* __restrict__ dst, int* __restrict__ bh)
{
    __shared__ int lhist[NBKT];
    const int t = threadIdx.x, blk = blockIdx.x;
    lhist[t] = 0;
    __syncthreads();
    const int e0 = blk * CHUNK1, e1 = e0 + CHUNK1;
    for (int e = e0 + t; e < e1; e += 256)
        atomicAdd(&lhist[(unsigned)dst[e] / BKTW], 1);
    __syncthreads();
    bh[t * NBLK1 + blk] = lhist[t];
}

__global__ __launch_bounds__(256) void scan_buckets_kernel(
    int* __restrict__ bh, int* __restrict__ btotal)
{
    __shared__ int sb[256];
    const int t = threadIdx.x, b = blockIdx.x;
    const int v = (t < NBLK1) ? bh[b * NBLK1 + t] : 0;
    sb[t] = v;
    __syncthreads();
    int x = v;
    for (int off = 1; off < 256; off <<= 1) {
        const int add = (t >= off) ? sb[t - off] : 0;
        __syncthreads();
        x += add;
        sb[t] = x;
        __syncthreads();
    }
    if (t < NBLK1) bh[b * NBLK1 + t] = x - v;
    if (t == 255) btotal[b] = x;
}

__global__ __launch_bounds__(256) void scan_totals_kernel(
    const int* __restrict__ btotal, int* __restrict__ bstart)
{
    __shared__ int sb[256];
    const int t = threadIdx.x;
    const int v = btotal[t];
    sb[t] = v;
    __syncthreads();
    int x = v;
    for (int off = 1; off < 256; off <<= 1) {
        const int add = (t >= off) ? sb[t - off] : 0;
        __syncthreads();
        x += add;
        sb[t] = x;
        __syncthreads();
    }
    bstart[t] = x - v;
    if (t == 255) bstart[256] = x;
}

__global__ __launch_bounds__(256) void scatter_bucket_kernel(
    const int* __restrict__ src, const int* __restrict__ dst,
    const int* __restrict__ bh, const int* __restrict__ bstart,
    int* __restrict__ gbuf)
{
    __shared__ int lbase[NBKT];
    __shared__ int lcur[NBKT];
    const int t = threadIdx.x, blk = blockIdx.x;
    lbase[t] = bstart[t] + bh[t * NBLK1 + blk];
    lcur[t] = 0;
    __syncthreads();
    const int e0 = blk * CHUNK1, e1 = e0 + CHUNK1;
    for (int e = e0 + t; e < e1; e += 256) {
        const int d = dst[e];
        const unsigned b = (unsigned)d / BKTW;
        const int ld = d - (int)b * BKTW;
        const int r = atomicAdd(&lcur[b], 1);
        gbuf[lbase[b] + r] = (ld << 16) | src[e];
    }
}

__global__ __launch_bounds__(256) void sort_bucket_kernel(
    const int* __restrict__ gbuf, const int* __restrict__ bstart,
    int* __restrict__ perm, int* __restrict__ rowp)
{
    __shared__ int lhist[NBKT];
    __shared__ int lscan[NBKT];
    __shared__ int lcur[NBKT];
    const int t = threadIdx.x, b = blockIdx.x;
    const int base = bstart[b];
    const int cnt  = bstart[b + 1] - base;
    const int n0   = b * BKTW;

    lhist[t] = 0;
    lcur[t] = 0;
    __syncthreads();
    for (int i = t; i < cnt; i += 256)
        atomicAdd(&lhist[gbuf[base + i] >> 16], 1);
    __syncthreads();

    const int v = lhist[t];
    lscan[t] = v;
    __syncthreads();
    int x = v;
    for (int off = 1; off < 256; off <<= 1) {
        const int add = (t >= off) ? lscan[t - off] : 0;
        __syncthreads();
        x += add;
        lscan[t] = x;
        __syncthreads();
    }
    const int excl = x - v;
    __syncthreads();
    lscan[t] = excl;

    const int n = n0 + t;
    if (t < BKTW && n < N_NODES) rowp[n] = base + excl;
    if (b == NBKT - 1 && t == 0) rowp[N_NODES] = bstart[NBKT];
    __syncthreads();

    for (int i = t; i < cnt; i += 256) {
        const int e = gbuf[base + i];
        const int ld = e >> 16;
        const int r = atomicAdd(&lcur[ld], 1);
        perm[base + lscan[ld] + r] = e & 0xFFFF;
    }
}

// ---------------------------------------------------------------------------
// gather v4: channel-sliced, XCD-affine. slice = blockIdx&3 -> with round-robin
// XCD = blockIdx&7, each XCD touches only its slice's 3.2MB of z (1 line/row)
// -> fits 4MB L2. Block = 256 thr = 4 waves = 4 nodes x 1 slice. Wave: lane =
// (edge-slot q = l>>4, channel-pair ci = l&15); c = slice*32 + ci*2; head
// h = c>>4 in {2s,2s+1} -> exp work partitions exactly across slices (no
// redundancy). 8 edges/round (2 z-loads/lane), weights software-pipelined one
// round ahead. No LDS, no barriers; final 4-way reduce via 2 shfl_xor.
// ---------------------------------------------------------------------------
__global__ __launch_bounds__(256) void gather_kernel(
    const int* __restrict__ row_ptr, const int* __restrict__ perm,
    const _Float16* __restrict__ z,
    const float* __restrict__ s_src, const float* __restrict__ s_dst,
    float* __restrict__ out, const int apply_elu)
{
    const int g     = blockIdx.x;
    const int slice = g & 3;
    const int group = g >> 2;
    const int wv    = threadIdx.x >> 6;
    const int l     = threadIdx.x & 63;
    const int n     = group * 4 + wv;          // grid sized so n < N_NODES

    const int q  = l >> 4;                     // edge slot (edges q, q+4)
    const int ci = l & 15;
    const int c0 = slice * 32 + ci * 2;        // channel pair
    const int h  = c0 >> 4;                    // head (2*slice or 2*slice+1)

    const int start = row_ptr[n];
    const int end   = row_ptr[n + 1];
    const float sd  = s_dst[n * 8 + h];

    float acc0 = 0.f, acc1 = 0.f, wsum = 0.f;

    // prologue: weights for round 0 (edges start+q, start+q+4)
    int se_a = 0, se_b = 0;
    float w_a = 0.f, w_b = 0.f;
    {
        const int ja = start + q, jb = start + q + 4;
        if (ja < end) {
            se_a = perm[ja];
            float s = s_src[se_a * 8 + h] + sd;
            s = s > 0.f ? s : NEG_SLOPE * s;
            w_a = __expf(s);
        }
        if (jb < end) {
            se_b = perm[jb];
            float s = s_src[se_b * 8 + h] + sd;
            s = s > 0.f ? s : NEG_SLOPE * s;
            w_b = __expf(s);
        }
    }

    for (int j0 = start; j0 < end; j0 += 8) {
        // z loads for current round (issue first, consume after prefetch)
        const v2h za = *(const v2h*)&z[se_a * 128 + c0];
        const v2h zb = *(const v2h*)&z[se_b * 128 + c0];
        const float wa = w_a, wb = w_b;

        // prefetch next round's weights (hides perm/s_src latency)
        se_a = 0; se_b = 0; w_a = 0.f; w_b = 0.f;
        {
            const int ja = j0 + 8 + q, jb = j0 + 12 + q;
            if (ja < end) {
                se_a = perm[ja];
                float s = s_src[se_a * 8 + h] + sd;
                s = s > 0.f ? s : NEG_SLOPE * s;
                w_a = __expf(s);
            }
            if (jb < end) {
                se_b = perm[jb];
                float s = s_src[se_b * 8 + h] + sd;
                s = s > 0.f ? s : NEG_SLOPE * s;
                w_b = __expf(s);
            }
        }

        wsum += wa + wb;
        acc0 = fmaf(wa, (float)za[0], acc0);
        acc1 = fmaf(wa, (float)za[1], acc1);
        acc0 = fmaf(wb, (float)zb[0], acc0);
        acc1 = fmaf(wb, (float)zb[1], acc1);
    }

    // reduce over the 4 edge-slots (lanes ci, ci+16, ci+32, ci+48)
    acc0 += __shfl_xor(acc0, 16); acc0 += __shfl_xor(acc0, 32);
    acc1 += __shfl_xor(acc1, 16); acc1 += __shfl_xor(acc1, 32);
    wsum += __shfl_xor(wsum, 16); wsum += __shfl_xor(wsum, 32);

    if (l < 16) {
        const float inv = (wsum > 0.f) ? 1.f / wsum : 0.f;
        float o0 = acc0 * inv;
        float o1 = acc1 * inv;
        if (apply_elu) {
            o0 = o0 > 0.f ? o0 : expm1f(o0);
            o1 = o1 > 0.f ? o1 : expm1f(o1);
        }
        *(float2*)&out[n * 128 + c0] = make_float2(o0, o1);
    }
}

extern "C" void kernel_launch(void* const* d_in, const int* in_sizes, int n_in,
                              void* d_out, int out_size, void* d_ws, size_t ws_size,
                              hipStream_t stream) {
    const float* x    = (const float*)d_in[0];
    const int*   src  = (const int*)d_in[1];
    const int*   dst  = (const int*)d_in[2];
    const float* W1   = (const float*)d_in[3];
    const float* a1s  = (const float*)d_in[4];
    const float* a1d  = (const float*)d_in[5];
    const float* W2   = (const float*)d_in[6];
    const float* a2s  = (const float*)d_in[7];
    const float* a2d  = (const float*)d_in[8];
    float* out = (float*)d_out;

    // workspace carve
    char* p = (char*)d_ws;
    _Float16* z  = (_Float16*)p;  p += (size_t)N_NODES * 128 * 2;       // 12.8MB
    float* ssrc  = (float*)p;     p += (size_t)N_NODES * 8 * 4;         // 1.6MB
    float* sdst  = (float*)p;     p += (size_t)N_NODES * 8 * 4;         // 1.6MB
    int*   rowp  = (int*)p;       p += ((size_t)N_NODES + 4) * 4;       // 200KB
    int*   bh    = (int*)p;       p += (size_t)NBKT * NBLK1 * 4;        // 205KB
    int*   btot  = (int*)p;       p += (size_t)NBKT * 4;
    int*   bstart= (int*)p;       p += ((size_t)NBKT + 4) * 4;
    int*   gbuf  = (int*)p;       p += (size_t)N_EDGES * 4;             // 6.4MB
    int*   perm  = (int*)p;       p += (size_t)N_EDGES * 4;             // 6.4MB

    const int PROJ_GRID   = 391;
    const int SCORE_GRID  = (N_NODES * 8 + 255) / 256;
    const int GATHER_GRID = (N_NODES / 4) * 4;   // groups of 4 nodes x 4 slices

    // ---- CSR build (shared by both layers) ----
    hist_bucket_kernel<<<NBLK1, 256, 0, stream>>>(dst, bh);
    scan_buckets_kernel<<<NBKT, 256, 0, stream>>>(bh, btot);
    scan_totals_kernel<<<1, 256, 0, stream>>>(btot, bstart);
    scatter_bucket_kernel<<<NBLK1, 256, 0, stream>>>(src, dst, bh, bstart, gbuf);
    sort_bucket_kernel<<<NBKT, 256, 0, stream>>>(gbuf, bstart, perm, rowp);

    // ---- layer 1 ----
    proj_mfma_kernel<<<PROJ_GRID, 256, 0, stream>>>(x, W1, z);
    score_kernel<<<SCORE_GRID, 256, 0, stream>>>(z, a1s, a1d, ssrc, sdst);
    gather_kernel<<<GATHER_GRID, 256, 0, stream>>>(rowp, perm, z, ssrc, sdst, out, 1);

    // ---- layer 2 ----
    proj_mfma_kernel<<<PROJ_GRID, 256, 0, stream>>>(out, W2, z);
    score_kernel<<<SCORE_GRID, 256, 0, stream>>>(z, a2s, a2d, ssrc, sdst);
    gather_kernel<<<GATHER_GRID, 256, 0, stream>>>(rowp, perm, z, ssrc, sdst, out, 0);
}

// Round 9
// 232.525 us; speedup vs baseline: 2.0114x; 2.0114x over previous
//
#include <hip/hip_runtime.h>
#include <hip/hip_bf16.h>

#define N_NODES 50000
#define N_EDGES 1600000
#define NEG_SLOPE 0.01f
#define WPAD 136   // k-stride (fp16) for LDS-staged W

#define NBKT 256   // dst buckets
#define BKTW 196   // bucket width: 196*256 = 50176 >= 50000
#define NBLK1 200  // pass-1 blocks
#define CHUNK1 8000 // 200*8000 = 1.6M edges exactly

typedef _Float16 v8h __attribute__((ext_vector_type(8)));
typedef float v4f __attribute__((ext_vector_type(4)));

// ---------------------------------------------------------------------------
// proj: z[n, h*16+col] = sum_d x[n,d] * W[h,d,col], fp16 MFMA 16x16x32.
// (unchanged)
// ---------------------------------------------------------------------------
__global__ __launch_bounds__(256) void proj_mfma_kernel(
    const float* __restrict__ x,
    const float* __restrict__ W,
    _Float16* __restrict__ z)
{
    __shared__ _Float16 Wl[128 * WPAD];

    const int t = threadIdx.x;
    for (int i = t; i < 16384; i += 256) {
        const int h = i >> 11, k = (i >> 4) & 127, col = i & 15;
        Wl[(h * 16 + col) * WPAD + k] = (_Float16)W[i];
    }
    __syncthreads();

    const int wid = t >> 6;
    const int l   = t & 63;
    const int lc  = l & 15;
    const int kg  = l >> 4;

    const int nwaves = gridDim.x * 4;
    for (int tile = blockIdx.x * 4 + wid; tile < N_NODES / 16; tile += nwaves) {
        const int n0 = tile * 16;
        v4f acc[8];
#pragma unroll
        for (int ht = 0; ht < 8; ht++) acc[ht] = (v4f)0.f;

#pragma unroll
        for (int kb = 0; kb < 4; kb++) {
            const float4* xp = (const float4*)&x[(n0 + lc) * 128 + kb * 32 + kg * 8];
            const float4 xa = xp[0];
            const float4 xb = xp[1];
            v8h a;
            a[0] = (_Float16)xa.x; a[1] = (_Float16)xa.y;
            a[2] = (_Float16)xa.z; a[3] = (_Float16)xa.w;
            a[4] = (_Float16)xb.x; a[5] = (_Float16)xb.y;
            a[6] = (_Float16)xb.z; a[7] = (_Float16)xb.w;
#pragma unroll
            for (int ht = 0; ht < 8; ht++) {
                const v8h b = *(const v8h*)&Wl[(ht * 16 + lc) * WPAD + kb * 32 + kg * 8];
                acc[ht] = __builtin_amdgcn_mfma_f32_16x16x32_f16(a, b, acc[ht], 0, 0, 0);
            }
        }

        _Float16* zp = &z[(n0 + 4 * kg) * 128 + lc];
#pragma unroll
        for (int ht = 0; ht < 8; ht++)
#pragma unroll
            for (int i = 0; i < 4; i++)
                zp[i * 128 + ht * 16] = (_Float16)acc[ht][i];
    }
}

// ---------------------------------------------------------------------------
// score: s_src[n,h], s_dst[n,h] from fp16 z. (unchanged)
// ---------------------------------------------------------------------------
__global__ __launch_bounds__(256) void score_kernel(
    const _Float16* __restrict__ z,
    const float* __restrict__ a_src, const float* __restrict__ a_dst,
    float* __restrict__ s_src, float* __restrict__ s_dst)
{
    __shared__ float asl[128], adl[128];
    const int t = threadIdx.x;
    if (t < 128) { asl[t] = a_src[t]; adl[t] = a_dst[t]; }
    __syncthreads();

    const int idx = blockIdx.x * 256 + t;
    if (idx >= N_NODES * 8) return;
    const int n = idx >> 3, h = idx & 7;

    const v8h z0 = *(const v8h*)&z[n * 128 + h * 16];
    const v8h z1 = *(const v8h*)&z[n * 128 + h * 16 + 8];
    float ss = 0.f, sd = 0.f;
#pragma unroll
    for (int j = 0; j < 8; j++) {
        ss = fmaf((float)z0[j], asl[h * 16 + j], ss);
        sd = fmaf((float)z0[j], adl[h * 16 + j], sd);
    }
#pragma unroll
    for (int j = 0; j < 8; j++) {
        ss = fmaf((float)z1[j], asl[h * 16 + 8 + j], ss);
        sd = fmaf((float)z1[j], adl[h * 16 + 8 + j], sd);
    }
    s_src[idx] = ss;
    s_dst[idx] = sd;
}

// ---------------------------------------------------------------------------
// CSR build (unchanged): two-level bucket sort, block-local writes.
// ---------------------------------------------------------------------------
__global__ __launch_bounds__(256) void hist_bucket_kernel(
    const int* __restrict__ dst, int* __restrict__ bh)
{
    __shared__ int lhist[NBKT];
    const int t = threadIdx.x, blk = blockIdx.x;
    lhist[t] = 0;
    __syncthreads();
    const int e0 = blk * CHUNK1, e1 = e0 + CHUNK1;
    for (int e = e0 + t; e < e1; e += 256)
        atomicAdd(&lhist[(unsigned)dst[e] / BKTW], 1);
    __syncthreads();
    bh[t * NBLK1 + blk] = lhist[t];
}

__global__ __launch_bounds__(256) void scan_buckets_kernel(
    int* __restrict__ bh, int* __restrict__ btotal)
{
    __shared__ int sb[256];
    const int t = threadIdx.x, b = blockIdx.x;
    const int v = (t < NBLK1) ? bh[b * NBLK1 + t] : 0;
    sb[t] = v;
    __syncthreads();
    int x = v;
    for (int off = 1; off < 256; off <<= 1) {
        const int add = (t >= off) ? sb[t - off] : 0;
        __syncthreads();
        x += add;
        sb[t] = x;
        __syncthreads();
    }
    if (t < NBLK1) bh[b * NBLK1 + t] = x - v;
    if (t == 255) btotal[b] = x;
}

__global__ __launch_bounds__(256) void scan_totals_kernel(
    const int* __restrict__ btotal, int* __restrict__ bstart)
{
    __shared__ int sb[256];
    const int t = threadIdx.x;
    const int v = btotal[t];
    sb[t] = v;
    __syncthreads();
    int x = v;
    for (int off = 1; off < 256; off <<= 1) {
        const int add = (t >= off) ? sb[t - off] : 0;
        __syncthreads();
        x += add;
        sb[t] = x;
        __syncthreads();
    }
    bstart[t] = x - v;
    if (t == 255) bstart[256] = x;
}

__global__ __launch_bounds__(256) void scatter_bucket_kernel(
    const int* __restrict__ src, const int* __restrict__ dst,
    const int* __restrict__ bh, const int* __restrict__ bstart,
    int* __restrict__ gbuf)
{
    __shared__ int lbase[NBKT];
    __shared__ int lcur[NBKT];
    const int t = threadIdx.x, blk = blockIdx.x;
    lbase[t] = bstart[t] + bh[t * NBLK1 + blk];
    lcur[t] = 0;
    __syncthreads();
    const int e0 = blk * CHUNK1, e1 = e0 + CHUNK1;
    for (int e = e0 + t; e < e1; e += 256) {
        const int d = dst[e];
        const unsigned b = (unsigned)d / BKTW;
        const int ld = d - (int)b * BKTW;
        const int r = atomicAdd(&lcur[b], 1);
        gbuf[lbase[b] + r] = (ld << 16) | src[e];
    }
}

__global__ __launch_bounds__(256) void sort_bucket_kernel(
    const int* __restrict__ gbuf, const int* __restrict__ bstart,
    int* __restrict__ perm, int* __restrict__ rowp)
{
    __shared__ int lhist[NBKT];
    __shared__ int lscan[NBKT];
    __shared__ int lcur[NBKT];
    const int t = threadIdx.x, b = blockIdx.x;
    const int base = bstart[b];
    const int cnt  = bstart[b + 1] - base;
    const int n0   = b * BKTW;

    lhist[t] = 0;
    lcur[t] = 0;
    __syncthreads();
    for (int i = t; i < cnt; i += 256)
        atomicAdd(&lhist[gbuf[base + i] >> 16], 1);
    __syncthreads();

    const int v = lhist[t];
    lscan[t] = v;
    __syncthreads();
    int x = v;
    for (int off = 1; off < 256; off <<= 1) {
        const int add = (t >= off) ? lscan[t - off] : 0;
        __syncthreads();
        x += add;
        lscan[t] = x;
        __syncthreads();
    }
    const int excl = x - v;
    __syncthreads();
    lscan[t] = excl;

    const int n = n0 + t;
    if (t < BKTW && n < N_NODES) rowp[n] = base + excl;
    if (b == NBKT - 1 && t == 0) rowp[N_NODES] = bstart[NBKT];
    __syncthreads();

    for (int i = t; i < cnt; i += 256) {
        const int e = gbuf[base + i];
        const int ld = e >> 16;
        const int r = atomicAdd(&lcur[ld], 1);
        perm[base + lscan[ld] + r] = e & 0xFFFF;
    }
}

// ---------------------------------------------------------------------------
// gather v5: one wave per node, full 128 channels per wave (no slicing).
// Lane = (edge-subslot q = l>>4, chunk ci = l&15 -> channels 8ci..8ci+7,
// head hc = ci>>1). Round = 8 edges:
//  - weights computed ONCE per (edge,head) in (e8=l>>3, h8=l&7) layout,
//    distributed to FMA lanes via one __shfl (no LDS, no barriers);
//  - z loaded as dwordx4: lane's edges q, q+4 -> 2 load instrs/round cover
//    8 full 256B rows (1KB/instr);
//  - se from direct broadcast perm loads (L1-hit) -> z-address chain is
//    independent of the softmax chain; round r+1's z + s_src loads stay in
//    flight under round r's FMA consume (software pipeline depth ~2).
// Final: cross-q reduce via shfl_xor(16,32); lanes 0..15 write 2x float4.
// ---------------------------------------------------------------------------
__global__ __launch_bounds__(256) void gather_kernel(
    const int* __restrict__ row_ptr, const int* __restrict__ perm,
    const _Float16* __restrict__ z,
    const float* __restrict__ s_src, const float* __restrict__ s_dst,
    float* __restrict__ out, const int apply_elu)
{
    const int wv = threadIdx.x >> 6;
    const int l  = threadIdx.x & 63;
    const int n  = blockIdx.x * 4 + wv;   // grid = N/4 exactly

    const int q  = l >> 4;        // FMA edge subslot (edges q, q+4 per round)
    const int ci = l & 15;        // channel chunk
    const int hc = ci >> 1;       // head of this chunk
    const int e8 = l >> 3;        // weight-phase edge slot 0..7
    const int h8 = l & 7;         // weight-phase head

    const int start = row_ptr[n];
    const int end   = row_ptr[n + 1];
    const float sd8 = s_dst[n * 8 + h8];

    float acc[8];
#pragma unroll
    for (int i = 0; i < 8; i++) acc[i] = 0.f;
    float wsum = 0.f;

    // ---- prologue: round 0 weights + z ----
    float w_cur = 0.f;
    {
        const int j = start + e8;
        if (j < end) {
            const int se = perm[j];
            float s = s_src[se * 8 + h8] + sd8;
            s = s > 0.f ? s : NEG_SLOPE * s;
            w_cur = __expf(s);
        }
    }
    int sea = 0, seb = 0;
    {
        const int ja = start + q, jb = start + q + 4;
        if (ja < end) sea = perm[ja];
        if (jb < end) seb = perm[jb];
    }
    v8h za = *(const v8h*)&z[(size_t)sea * 128 + ci * 8];
    v8h zb = *(const v8h*)&z[(size_t)seb * 128 + ci * 8];

    for (int j0 = start; j0 < end; j0 += 8) {
        // ---- prefetch round r+1 (weights + se + z) ----
        float w_nxt = 0.f;
        {
            const int j = j0 + 8 + e8;
            if (j < end) {
                const int se = perm[j];
                float s = s_src[se * 8 + h8] + sd8;
                s = s > 0.f ? s : NEG_SLOPE * s;
                w_nxt = __expf(s);
            }
        }
        int sea_n = 0, seb_n = 0;
        {
            const int ja = j0 + 8 + q, jb = j0 + 12 + q;
            if (ja < end) sea_n = perm[ja];
            if (jb < end) seb_n = perm[jb];
        }
        v8h za_n = *(const v8h*)&z[(size_t)sea_n * 128 + ci * 8];
        v8h zb_n = *(const v8h*)&z[(size_t)seb_n * 128 + ci * 8];

        // ---- consume round r ----
        const float wa = __shfl(w_cur, q * 8 + hc);
        const float wb = __shfl(w_cur, (q + 4) * 8 + hc);
        wsum += wa + wb;
#pragma unroll
        for (int i = 0; i < 8; i++) acc[i] = fmaf(wa, (float)za[i], acc[i]);
#pragma unroll
        for (int i = 0; i < 8; i++) acc[i] = fmaf(wb, (float)zb[i], acc[i]);

        w_cur = w_nxt;
        za = za_n; zb = zb_n;
    }

    // ---- reduce across the 4 edge subslots ----
#pragma unroll
    for (int i = 0; i < 8; i++) {
        acc[i] += __shfl_xor(acc[i], 16);
        acc[i] += __shfl_xor(acc[i], 32);
    }
    wsum += __shfl_xor(wsum, 16);
    wsum += __shfl_xor(wsum, 32);

    if (l < 16) {
        const float inv = (end > start) ? 1.f / wsum : 0.f;
        float o[8];
#pragma unroll
        for (int i = 0; i < 8; i++) {
            float v = acc[i] * inv;
            if (apply_elu) v = v > 0.f ? v : expm1f(v);
            o[i] = v;
        }
        float4* op = (float4*)&out[n * 128 + ci * 8];
        op[0] = make_float4(o[0], o[1], o[2], o[3]);
        op[1] = make_float4(o[4], o[5], o[6], o[7]);
    }
}

extern "C" void kernel_launch(void* const* d_in, const int* in_sizes, int n_in,
                              void* d_out, int out_size, void* d_ws, size_t ws_size,
                              hipStream_t stream) {
    const float* x    = (const float*)d_in[0];
    const int*   src  = (const int*)d_in[1];
    const int*   dst  = (const int*)d_in[2];
    const float* W1   = (const float*)d_in[3];
    const float* a1s  = (const float*)d_in[4];
    const float* a1d  = (const float*)d_in[5];
    const float* W2   = (const float*)d_in[6];
    const float* a2s  = (const float*)d_in[7];
    const float* a2d  = (const float*)d_in[8];
    float* out = (float*)d_out;

    // workspace carve
    char* p = (char*)d_ws;
    _Float16* z  = (_Float16*)p;  p += (size_t)N_NODES * 128 * 2;       // 12.8MB
    float* ssrc  = (float*)p;     p += (size_t)N_NODES * 8 * 4;         // 1.6MB
    float* sdst  = (float*)p;     p += (size_t)N_NODES * 8 * 4;         // 1.6MB
    int*   rowp  = (int*)p;       p += ((size_t)N_NODES + 4) * 4;       // 200KB
    int*   bh    = (int*)p;       p += (size_t)NBKT * NBLK1 * 4;        // 205KB
    int*   btot  = (int*)p;       p += (size_t)NBKT * 4;
    int*   bstart= (int*)p;       p += ((size_t)NBKT + 4) * 4;
    int*   gbuf  = (int*)p;       p += (size_t)N_EDGES * 4;             // 6.4MB
    int*   perm  = (int*)p;       p += (size_t)N_EDGES * 4;             // 6.4MB

    const int PROJ_GRID   = 391;
    const int SCORE_GRID  = (N_NODES * 8 + 255) / 256;
    const int GATHER_GRID = N_NODES / 4;   // 12500 blocks x 4 waves

    // ---- CSR build (shared by both layers) ----
    hist_bucket_kernel<<<NBLK1, 256, 0, stream>>>(dst, bh);
    scan_buckets_kernel<<<NBKT, 256, 0, stream>>>(bh, btot);
    scan_totals_kernel<<<1, 256, 0, stream>>>(btot, bstart);
    scatter_bucket_kernel<<<NBLK1, 256, 0, stream>>>(src, dst, bh, bstart, gbuf);
    sort_bucket_kernel<<<NBKT, 256, 0, stream>>>(gbuf, bstart, perm, rowp);

    // ---- layer 1 ----
    proj_mfma_kernel<<<PROJ_GRID, 256, 0, stream>>>(x, W1, z);
    score_kernel<<<SCORE_GRID, 256, 0, stream>>>(z, a1s, a1d, ssrc, sdst);
    gather_kernel<<<GATHER_GRID, 256, 0, stream>>>(rowp, perm, z, ssrc, sdst, out, 1);

    // ---- layer 2 ----
    proj_mfma_kernel<<<PROJ_GRID, 256, 0, stream>>>(out, W2, z);
    score_kernel<<<SCORE_GRID, 256, 0, stream>>>(z, a2s, a2d, ssrc, sdst);
    gather_kernel<<<GATHER_GRID, 256, 0, stream>>>(rowp, perm, z, ssrc, sdst, out, 0);
}